// Round 16
// baseline (412.735 us; speedup 1.0000x reference)
//
#include <hip/hip_runtime.h>

#define NPTS 2048
#define TOPK 32
#define RPB  8        // rows per block in phase 1
#define MAINBLKS 30   // fixpoint blocks; tail handled densely
#define SPLITB 20     // diagnostic split: A = [0,20), B = [20,30)+tail
#define TAILROWS (NPTS - MAINBLKS * 64)  // 128

typedef float v2f __attribute__((ext_vector_type(2)));
typedef unsigned int u32;
typedef u32 v2u __attribute__((ext_vector_type(2)));
typedef unsigned long long u64;

// ---------- helpers ----------
static __device__ __forceinline__ u32 umin32(u32 a, u32 b) { return b < a ? b : a; }
static __device__ __forceinline__ u64 umin64(u64 a, u64 b) { return b < a ? b : a; }

template <int CTRL>
static __device__ __forceinline__ u32 dpp_min(u32 m) {
  return umin32(m, (u32)__builtin_amdgcn_mov_dpp((int)m, CTRL, 0xF, 0xF, true));
}
static __device__ __forceinline__ u32 x16_min(u32 m) {
#if __has_builtin(__builtin_amdgcn_permlane16_swap)
  auto r = __builtin_amdgcn_permlane16_swap((int)m, (int)m, false, false);
  return umin32(m, umin32((u32)r[0], (u32)r[1]));
#else
  return umin32(m, (u32)__builtin_amdgcn_ds_swizzle((int)m, 0x401F));
#endif
}
static __device__ __forceinline__ u32 x32_min(u32 m) {
#if __has_builtin(__builtin_amdgcn_permlane32_swap)
  auto r = __builtin_amdgcn_permlane32_swap((int)m, (int)m, false, false);
  return umin32(m, umin32((u32)r[0], (u32)r[1]));
#else
  return umin32(m, (u32)__shfl_xor((int)m, 32, 64));
#endif
}
static __device__ __forceinline__ u32 sext_bit(u32 mask, int c) {
#if __has_builtin(__builtin_amdgcn_sbfe)
  return (u32)__builtin_amdgcn_sbfe((int)mask, c, 1);
#else
  return (u32)(((int)(mask << (31 - c))) >> 31);
#endif
}

template <int CTRL>
static __device__ __forceinline__ u64 dpp_min64(u64 k) {
  unsigned lo = (unsigned)k, hi = (unsigned)(k >> 32);
  unsigned olo = (unsigned)__builtin_amdgcn_mov_dpp((int)lo, CTRL, 0xF, 0xF, true);
  unsigned ohi = (unsigned)__builtin_amdgcn_mov_dpp((int)hi, CTRL, 0xF, 0xF, true);
  return umin64(k, ((u64)ohi << 32) | olo);
}
static __device__ __forceinline__ u64 x16_min64(u64 k) {
  unsigned lo = (unsigned)k, hi = (unsigned)(k >> 32);
#if __has_builtin(__builtin_amdgcn_permlane16_swap)
  auto rlo = __builtin_amdgcn_permlane16_swap(lo, lo, false, false);
  auto rhi = __builtin_amdgcn_permlane16_swap(hi, hi, false, false);
  u64 a = ((u64)rhi[0] << 32) | rlo[0];
  u64 b = ((u64)rhi[1] << 32) | rlo[1];
  return umin64(k, umin64(a, b));
#else
  unsigned olo = (unsigned)__builtin_amdgcn_ds_swizzle((int)lo, 0x401F);
  unsigned ohi = (unsigned)__builtin_amdgcn_ds_swizzle((int)hi, 0x401F);
  return umin64(k, ((u64)ohi << 32) | olo);
#endif
}
static __device__ __forceinline__ u64 x32_min64(u64 k) {
  unsigned lo = (unsigned)k, hi = (unsigned)(k >> 32);
#if __has_builtin(__builtin_amdgcn_permlane32_swap)
  auto rlo = __builtin_amdgcn_permlane32_swap(lo, lo, false, false);
  auto rhi = __builtin_amdgcn_permlane32_swap(hi, hi, false, false);
  u64 a = ((u64)rhi[0] << 32) | rlo[0];
  u64 b = ((u64)rhi[1] << 32) | rlo[1];
  return umin64(k, umin64(a, b));
#else
  unsigned olo = (unsigned)__shfl_xor((int)lo, 32, 64);
  unsigned ohi = (unsigned)__shfl_xor((int)hi, 32, 64);
  return umin64(k, ((u64)ohi << 32) | olo);
#endif
}
static __device__ __forceinline__ u64 wave_min_u64(u64 k) {
  k = dpp_min64<0xB1>(k);
  k = dpp_min64<0x4E>(k);
  k = dpp_min64<0x141>(k);
  k = dpp_min64<0x140>(k);
  k = x16_min64(k);
  k = x32_min64(k);
  return k;  // wave-uniform
}

#define FOR16(M) M(0) M(1) M(2) M(3) M(4) M(5) M(6) M(7) \
                 M(8) M(9) M(10) M(11) M(12) M(13) M(14) M(15)

// Lane's 32 target columns in NAMED registers, as float2 pairs.
#define LOADP(h) \
  v2f TX##h, TY##h, TZ##h, TQ##h; \
  { float x0 = tb[6*h+0], y0 = tb[6*h+1], z0 = tb[6*h+2]; \
    float x1 = tb[6*h+3], y1 = tb[6*h+4], z1 = tb[6*h+5]; \
    TX##h = (v2f){x0, x1}; TY##h = (v2f){y0, y1}; TZ##h = (v2f){z0, z1}; \
    TQ##h = (v2f){x0*x0 + y0*y0 + z0*z0, x1*x1 + y1*y1 + z1*z1}; }

// ---------- phase 1: exact per-row sorted top-32, incremental tree ----------
#define DISTK(h) u64 KA##h, KB##h; { \
  v2f dot = __builtin_elementwise_fma(TX##h, Xv, \
              __builtin_elementwise_fma(TY##h, Yv, TZ##h * Zv)); \
  v2f dd  = __builtin_elementwise_fma(m2v, dot, TQ##h); \
  v2f d2  = Qv + dd; \
  float c0 = fmaxf(d2.x, 1e-12f), c1 = fmaxf(d2.y, 1e-12f); \
  KA##h = ((u64)(u32)__float_as_int(c0) << 32) | (u32)(base + 2*(h)); \
  KB##h = ((u64)(u32)__float_as_int(c1) << 32) | (u32)(base + 2*(h) + 1); }

#define G4(a, b, c, d) umin64(umin64(a, b), umin64(c, d))
#define ZG(c, KV, RL) case (c): KV = own ? ~0ULL : KV; goto RL;

__global__ __launch_bounds__(64, 2) void emd_topk_kernel(
    const float* __restrict__ pred, const float* __restrict__ target,
    u64* __restrict__ lists) {
  const int blk = blockIdx.x;
  const int b  = blk / (NPTS / RPB);
  const int r0 = (blk % (NPTS / RPB)) * RPB;
  const int lane = threadIdx.x;
  const float* p = pred + (size_t)b * NPTS * 3;
  const float* t = target + (size_t)b * NPTS * 3;

  const float* tb = t + (size_t)lane * 32 * 3;
  FOR16(LOADP)
  const int base = lane << 5;
  const v2f m2v = {-2.f, -2.f};

#pragma unroll 1
  for (int rr = 0; rr < RPB; ++rr) {
    const int i = r0 + rr;
    const float X = p[3 * i], Y = p[3 * i + 1], Z = p[3 * i + 2];
    const float Q = fmaf(X, X, fmaf(Y, Y, Z * Z));
    const v2f Xv = {X, X}, Yv = {Y, Y}, Zv = {Z, Z}, Qv = {Q, Q};
    FOR16(DISTK)

    u64 g0 = G4(KA0, KB0, KA1, KB1),   g1 = G4(KA2, KB2, KA3, KB3);
    u64 g2 = G4(KA4, KB4, KA5, KB5),   g3 = G4(KA6, KB6, KA7, KB7);
    u64 g4 = G4(KA8, KB8, KA9, KB9),   g5 = G4(KA10, KB10, KA11, KB11);
    u64 g6 = G4(KA12, KB12, KA13, KB13), g7 = G4(KA14, KB14, KA15, KB15);
    u64 h0 = umin64(g0, g1), h1 = umin64(g2, g3);
    u64 h2 = umin64(g4, g5), h3 = umin64(g6, g7);
    u64 q0 = umin64(h0, h1), q1 = umin64(h2, h3);
    u64 root = umin64(q0, q1);

    u64* out = lists + ((size_t)b * NPTS + i) * TOPK;
#pragma unroll 1
    for (int e = 0; e < TOPK; ++e) {
      u64 m = wave_min_u64(root);
      if (lane == 0) out[e] = m;
      if (e == TOPK - 1) break;
      const u32 col = (u32)m & (u32)(NPTS - 1);  // wave-uniform
      const bool own = (lane == (int)(col >> 5));
      const u32 k5 = col & 31u;
      switch (k5) {
        ZG(0,  KA0,  R0) ZG(1,  KB0,  R0) ZG(2,  KA1,  R0) ZG(3,  KB1,  R0)
        ZG(4,  KA2,  R1) ZG(5,  KB2,  R1) ZG(6,  KA3,  R1) ZG(7,  KB3,  R1)
        ZG(8,  KA4,  R2) ZG(9,  KB4,  R2) ZG(10, KA5,  R2) ZG(11, KB5,  R2)
        ZG(12, KA6,  R3) ZG(13, KB6,  R3) ZG(14, KA7,  R3) ZG(15, KB7,  R3)
        ZG(16, KA8,  R4) ZG(17, KB8,  R4) ZG(18, KA9,  R4) ZG(19, KB9,  R4)
        ZG(20, KA10, R5) ZG(21, KB10, R5) ZG(22, KA11, R5) ZG(23, KB11, R5)
        ZG(24, KA12, R6) ZG(25, KB12, R6) ZG(26, KA13, R6) ZG(27, KB13, R6)
        ZG(28, KA14, R7) ZG(29, KB14, R7) ZG(30, KA15, R7) ZG(31, KB15, R7)
        default: __builtin_unreachable();
      }
      R0: g0 = G4(KA0, KB0, KA1, KB1);     h0 = umin64(g0, g1); q0 = umin64(h0, h1); root = umin64(q0, q1); continue;
      R1: g1 = G4(KA2, KB2, KA3, KB3);     h0 = umin64(g0, g1); q0 = umin64(h0, h1); root = umin64(q0, q1); continue;
      R2: g2 = G4(KA4, KB4, KA5, KB5);     h1 = umin64(g2, g3); q0 = umin64(h0, h1); root = umin64(q0, q1); continue;
      R3: g3 = G4(KA6, KB6, KA7, KB7);     h1 = umin64(g2, g3); q0 = umin64(h0, h1); root = umin64(q0, q1); continue;
      R4: g4 = G4(KA8, KB8, KA9, KB9);     h2 = umin64(g4, g5); q1 = umin64(h2, h3); root = umin64(q0, q1); continue;
      R5: g5 = G4(KA10, KB10, KA11, KB11); h2 = umin64(g4, g5); q1 = umin64(h2, h3); root = umin64(q0, q1); continue;
      R6: g6 = G4(KA12, KB12, KA13, KB13); h3 = umin64(g6, g7); q1 = umin64(h2, h3); root = umin64(q0, q1); continue;
      R7: g7 = G4(KA14, KB14, KA15, KB15); h3 = umin64(g6, g7); q1 = umin64(h2, h3); root = umin64(q0, q1); continue;
    }
  }
}

// ---------- phase 2: pipelined DA, atomicMin-return cascade, split ----------
// Template over block range for A/B diagnostic split. Algorithm identical to
// rounds 12-15 (absmax 0); cascade protocol now uses atomicMin's return value
// (one LDS op per chase hop instead of write+read), victims discover
// displacement via one claim read per round.

#define LD16(M) M(0) M(1) M(2) M(3) M(4) M(5) M(6) M(7) \
                M(8) M(9) M(10) M(11) M(12) M(13) M(14) M(15)
#define DECLA(j) uint4 A##j;
#define LDA(j)   A##j = Lr[j];
#define WRCD(j)  { dst[(2*(j)) * 64 + lane]     = ((u64)A##j.y << 32) | A##j.x; \
                   dst[(2*(j) + 1) * 64 + lane] = ((u64)A##j.w << 32) | A##j.z; }

#define ADVANCE() { \
    alive &= ~(1u << rank); \
    if (alive == 0u) { exh = true; } \
    else { \
      rank = (u32)__ffs(alive) - 1u; \
      cur = cl[rank * 64 + lane]; \
      col = (u32)cur & 2047u; \
    } }

// atomicMin-return cascade: chase hop = 1 LDS atomic (returns old).
#define CASCADE() { \
    int guard_ = 0; \
    while (true) { \
      bool changed_ = false; \
      if (!committed && !exh) { \
        if (holding && vclaim[col] < (u32)lane) { \
          holding = false; \
          ADVANCE() \
          changed_ = true; \
        } \
        int g2_ = 0; \
        while (!holding && !exh) { \
          u32 old_ = atomicMin(&claimCur[col], (u32)lane); \
          if (old_ >= (u32)lane) { holding = true; break; } \
          ADVANCE() \
          changed_ = true; \
          if (++g2_ > 40) break; \
        } \
      } \
      if (__ballot(changed_) == 0ULL) break; \
      if (++guard_ > 3000) break; \
    } }

template <int BLK0, int BLK1, bool DOTAIL>
__global__ __launch_bounds__(256, 1) void emd_seq_part(
    const float* __restrict__ pred, const float* __restrict__ target,
    const u64* __restrict__ lists, u32* __restrict__ bmws,
    float* __restrict__ psumws, float* __restrict__ batch_sums) {
  const int b = blockIdx.x;
  const int tid = threadIdx.x;
  const int w = tid >> 6, lane = tid & 63;
  const float* t = target + (size_t)b * NPTS * 3;
  const float* p = pred + (size_t)b * NPTS * 3;

  __shared__ float4 tt[NPTS];          // 32 KB
  __shared__ u64 cl64s[2][TOPK * 64];  // 32 KB
  __shared__ u32 claimb[2][NPTS];      // 16 KB
  __shared__ u32 fl[NPTS];             // 8 KB
  __shared__ u32 sbitmap[64];
  __shared__ float4 ppredb[2][64];
  __shared__ float4 tpred[TAILROWS];

  for (int j = tid; j < NPTS; j += 256) {
    float x = t[3 * j], y = t[3 * j + 1], z = t[3 * j + 2];
    tt[((j & 31) << 6) | ((j >> 5) ^ (j & 31))] =
        make_float4(x, y, z, fmaf(x, x, fmaf(y, y, z * z)));
  }
  if (tid < 64) sbitmap[tid] = (BLK0 == 0) ? 0u : bmws[b * 64 + tid];

  const u64* L = lists + (size_t)b * NPTS * TOPK;
  volatile u32* sbm = sbitmap;
  float psum = 0.f;

  const uint4* Lr;
  LD16(DECLA)

  // ---- prologue staging: block BLK0 into buf[BLK0&1]; prefetch BLK0+1 ----
  if (w == 1) {
    Lr = (const uint4*)(L + (size_t)(BLK0 * 64 + lane) * TOPK);
    LD16(LDA)
    u64* dst = &cl64s[BLK0 & 1][0];
    LD16(WRCD)
    if (BLK0 + 1 < BLK1) {
      Lr = (const uint4*)(L + (size_t)((BLK0 + 1) * 64 + lane) * TOPK);
      LD16(LDA)
    }
  } else if (w == 2) {
#pragma unroll
    for (int k = 0; k < 32; ++k) claimb[BLK0 & 1][k * 64 + lane] = ~0u;
  } else if (w == 3) {
    { const float* pr = p + (size_t)(BLK0 * 64 + lane) * 3;
      float X = pr[0], Y = pr[1], Z = pr[2];
      ppredb[BLK0 & 1][lane] = make_float4(X, Y, Z, fmaf(X, X, fmaf(Y, Y, Z * Z))); }
    if (DOTAIL) {
      { const float* pr = p + (size_t)(MAINBLKS * 64 + lane) * 3;
        float X = pr[0], Y = pr[1], Z = pr[2];
        tpred[lane] = make_float4(X, Y, Z, fmaf(X, X, fmaf(Y, Y, Z * Z))); }
      { const float* pr = p + (size_t)(MAINBLKS * 64 + 64 + lane) * 3;
        float X = pr[0], Y = pr[1], Z = pr[2];
        tpred[64 + lane] = make_float4(X, Y, Z, fmaf(X, X, fmaf(Y, Y, Z * Z))); }
    }
  }

#pragma unroll 1
  for (int blk = BLK0; blk < BLK1; ++blk) {
    __syncthreads();

    if (w == 1) {
      if (blk + 1 < BLK1) {
        u64* dst = &cl64s[(blk + 1) & 1][0];
        LD16(WRCD)
        if (blk + 2 < BLK1) {
          Lr = (const uint4*)(L + (size_t)((blk + 2) * 64 + lane) * TOPK);
          LD16(LDA)
        }
      }
    } else if (w == 2) {
      if (blk + 1 < BLK1) {
#pragma unroll
        for (int k = 0; k < 32; ++k) claimb[(blk + 1) & 1][k * 64 + lane] = ~0u;
      }
    } else if (w == 3) {
      if (blk + 1 < BLK1) {
        const float* pr = p + (size_t)((blk + 1) * 64 + lane) * 3;
        float X = pr[0], Y = pr[1], Z = pr[2];
        ppredb[(blk + 1) & 1][lane] =
            make_float4(X, Y, Z, fmaf(X, X, fmaf(Y, Y, Z * Z)));
      }
    } else {  // w == 0: consumer
      const u64* cl = &cl64s[blk & 1][0];
      u32* claimCur = &claimb[blk & 1][0];
      volatile u32* vclaim = claimCur;
      const float4* ppcur = &ppredb[blk & 1][0];

      u32 alive = 0u;
#pragma unroll
      for (int j = 0; j < 32; ++j) {
        u32 c = (u32)cl[j * 64 + lane] & 2047u;
        u32 wd = sbm[c >> 5];
        alive |= ((~(wd >> (c & 31u))) & 1u) << j;
      }

      bool committed = false;
      bool holding = false;
      bool exh = (alive == 0u);
      u32 rank = 0, col = 0;
      u64 cur = 0;
      if (!exh) {
        rank = (u32)__ffs(alive) - 1u;
        cur = cl[rank * 64 + lane];
        col = (u32)cur & 2047u;
      }
      CASCADE()

      bool flBuilt = false;
      u32 F = 0;
      int oguard = 0;
#pragma unroll 1
      while (true) {
        u64 exbl = __ballot(exh && !committed);
        if (exbl == 0ULL) break;
        int rstar = __ffsll(exbl) - 1;

        if (!committed && !exh && lane < rstar) {
          atomicOr(&sbitmap[col >> 5], 1u << (col & 31u));
          psum += sqrtf(__uint_as_float((u32)(cur >> 32)));
          committed = true;
        }

        if (!flBuilt) {
          u32 fw = ~sbm[lane];
          u32 cnt = __popc(fw);
          u32 pfx = cnt;
#pragma unroll
          for (int d = 1; d < 64; d <<= 1) {
            u32 o = (u32)__shfl_up((int)pfx, d, 64);
            if (lane >= d) pfx += o;
          }
          F = (u32)__shfl((int)pfx, 63, 64);
          pfx -= cnt;
          while (fw) {
            int bpos = __ffs(fw) - 1;
            fw &= fw - 1u;
            fl[pfx++] = ((u32)lane << 5) + (u32)bpos;
          }
          flBuilt = true;
        }

        u32 cst;
        {
          float4 P4 = ppcur[rstar];
          float X = P4.x, Y = P4.y, Z = P4.z, Q = P4.w;
          u64 mb = ~0ULL;
          for (u32 k = (u32)lane; k < F; k += 64) {
            u32 c = fl[k];
            u32 used = (sbm[c >> 5] >> (c & 31u)) & 1u;
            float4 c4 = tt[((c & 31u) << 6) | ((c >> 5) ^ (c & 31u))];
            float dot = fmaf(c4.x, X, fmaf(c4.y, Y, c4.z * Z));
            float d2 = Q + fmaf(-2.f, dot, c4.w);
            d2 = fmaxf(d2, 1e-12f);
            u64 kk = ((u64)(u32)__float_as_int(d2) << 32) | c;
            if (used) kk = ~0ULL;
            mb = umin64(mb, kk);
          }
          mb = wave_min_u64(mb);
          cst = (u32)mb & 2047u;
          if (lane == rstar) {
            psum += sqrtf(__uint_as_float((u32)(mb >> 32)));
            committed = true;
          }
        }
        u32 prev = vclaim[cst];
        if (lane == rstar) {
          atomicOr(&sbitmap[cst >> 5], 1u << (cst & 31u));
          atomicMin(&claimCur[cst], (u32)rstar);
        }
        if (prev != ~0u) {
          CASCADE()
        }
        if (++oguard > 80) break;
      }

      if (!committed) {
        atomicOr(&sbitmap[col >> 5], 1u << (col & 31u));
        psum += sqrtf(__uint_as_float((u32)(cur >> 32)));
      }
    }
  }

  __syncthreads();

  if (w == 0) {
    if (DOTAIL) {
      // ---- dense register tail over F free cols ----
      u32 fw = ~sbm[lane];
      u32 cnt = __popc(fw);
      u32 pfx = cnt;
#pragma unroll
      for (int d = 1; d < 64; d <<= 1) {
        u32 o = (u32)__shfl_up((int)pfx, d, 64);
        if (lane >= d) pfx += o;
      }
      u32 F = (u32)__shfl((int)pfx, 63, 64);
      pfx -= cnt;
      while (fw) {
        int bpos = __ffs(fw) - 1;
        fw &= fw - 1u;
        fl[pfx++] = ((u32)lane << 5) + (u32)bpos;
      }

      bool l0 = (u32)lane < F, l1 = (u32)(64 + lane) < F;
      u32 c0 = l0 ? fl[lane] : 0u;
      u32 c1 = l1 ? fl[64 + lane] : 0u;
      float4 t0 = tt[((c0 & 31u) << 6) | ((c0 >> 5) ^ (c0 & 31u))];
      float4 t1 = tt[((c1 & 31u) << 6) | ((c1 >> 5) ^ (c1 & 31u))];

#pragma unroll 1
      for (int r = 0; r < TAILROWS; ++r) {
        float4 P = tpred[r];
        float X = P.x, Y = P.y, Z = P.z, Q = P.w;
        float dot0 = fmaf(t0.x, X, fmaf(t0.y, Y, t0.z * Z));
        float d20 = fmaxf(Q + fmaf(-2.f, dot0, t0.w), 1e-12f);
        float dot1 = fmaf(t1.x, X, fmaf(t1.y, Y, t1.z * Z));
        float d21 = fmaxf(Q + fmaf(-2.f, dot1, t1.w), 1e-12f);
        u64 k0 = l0 ? (((u64)(u32)__float_as_int(d20) << 32) | c0) : ~0ULL;
        u64 k1 = l1 ? (((u64)(u32)__float_as_int(d21) << 32) | c1) : ~0ULL;
        u64 k = wave_min_u64(umin64(k0, k1));
        u32 wc = (u32)k & 2047u;
        l0 = l0 && (c0 != wc);
        l1 = l1 && (c1 != wc);
        if (lane == 0) psum += sqrtf(__uint_as_float((u32)(k >> 32)));
      }

      float v = psum;
      v += __shfl_xor(v, 1, 64);
      v += __shfl_xor(v, 2, 64);
      v += __shfl_xor(v, 4, 64);
      v += __shfl_xor(v, 8, 64);
      v += __shfl_xor(v, 16, 64);
      v += __shfl_xor(v, 32, 64);
      if (lane == 0) batch_sums[b] = v + psumws[b];
    } else {
      // handoff: bitmap + reduced partial sum
      bmws[b * 64 + lane] = sbitmap[lane];
      float v = psum;
      v += __shfl_xor(v, 1, 64);
      v += __shfl_xor(v, 2, 64);
      v += __shfl_xor(v, 4, 64);
      v += __shfl_xor(v, 8, 64);
      v += __shfl_xor(v, 16, 64);
      v += __shfl_xor(v, 32, 64);
      if (lane == 0) psumws[b] = v;
    }
  }
}

// ---------- legacy single-kernel path (round-5, proven; ws-too-small) ----------
#define DECLRU(h) v2u RU##h;
#define DIST(h) { \
  v2f dot = __builtin_elementwise_fma(TX##h, Xv, \
              __builtin_elementwise_fma(TY##h, Yv, TZ##h * Zv)); \
  v2f dd  = __builtin_elementwise_fma(m2v, dot, TQ##h); \
  v2f d2  = Qv + dd; \
  RU##h = (v2u){(u32)__float_as_int(d2.x), (u32)__float_as_int(d2.y)}; }
#define TOUR(h, c) { \
  u32 u0 = RU##h.x | sext_bit(usedmask, 2*h); \
  u32 u1 = RU##h.y | sext_bit(usedmask, 2*h + 1); \
  u32 pu = umin32(u0, u1); \
  u32 pk = (u1 < u0) ? (u32)(2*h + 1) : (u32)(2*h); \
  if (pu < bc##c) { bc##c = pu; kc##c = pk; } }

__global__ __launch_bounds__(64, 1) void emd_greedy_kernel(
    const float* __restrict__ pred, const float* __restrict__ target,
    float* __restrict__ batch_sums) {
  const int b = blockIdx.x, lane = threadIdx.x;
  const float* p = pred + (size_t)b * NPTS * 3;
  const float* t = target + (size_t)b * NPTS * 3;
  __shared__ float4 pp[NPTS + 2];
  for (int i = lane; i < NPTS; i += 64) {
    float x = p[3 * i], y = p[3 * i + 1], z = p[3 * i + 2];
    pp[i] = make_float4(x, y, z, x * x + y * y + z * z);
  }
  if (lane < 2) pp[NPTS + lane] = make_float4(0.f, 0.f, 0.f, 0.f);
  const float* tb = t + (size_t)lane * 32 * 3;
  FOR16(LOADP)
  FOR16(DECLRU)
  u32 usedmask = 0;
  float sum = 0.f;
  __syncthreads();
  const v2f m2v = {-2.f, -2.f};
  v2f Xv, Yv, Zv, Qv;
  {
    float4 A = pp[0];
    Xv = (v2f){A.x, A.x}; Yv = (v2f){A.y, A.y};
    Zv = (v2f){A.z, A.z}; Qv = (v2f){A.w, A.w};
    FOR16(DIST)
  }
  for (int i = 0; i < NPTS; ++i) {
    float4 An = pp[i + 1];
    u32 bc0 = ~0u, bc1 = ~0u, bc2 = ~0u, bc3 = ~0u;
    u32 kc0 = 0, kc1 = 0, kc2 = 0, kc3 = 0;
    TOUR(0, 0)  TOUR(1, 0)  TOUR(2, 0)  TOUR(3, 0)
    TOUR(4, 1)  TOUR(5, 1)  TOUR(6, 1)  TOUR(7, 1)
    TOUR(8, 2)  TOUR(9, 2)  TOUR(10, 2) TOUR(11, 2)
    TOUR(12, 3) TOUR(13, 3) TOUR(14, 3) TOUR(15, 3)
    bool s01 = bc1 < bc0; u32 v01 = s01 ? bc1 : bc0; u32 i01 = s01 ? kc1 : kc0;
    bool s23 = bc3 < bc2; u32 v23 = s23 ? bc3 : bc2; u32 i23 = s23 ? kc3 : kc2;
    bool sf  = v23 < v01; u32 bu  = sf ? v23 : v01; u32 bk  = sf ? i23 : i01;
    Xv = (v2f){An.x, An.x}; Yv = (v2f){An.y, An.y};
    Zv = (v2f){An.z, An.z}; Qv = (v2f){An.w, An.w};
    FOR16(DIST)
    u32 m = bu;
    m = dpp_min<0xB1>(m); m = dpp_min<0x4E>(m);
    m = dpp_min<0x141>(m); m = dpp_min<0x140>(m);
    m = x16_min(m); m = x32_min(m);
    u64 mk = __ballot(bu == m);
    int first = __ffsll(mk) - 1;
    usedmask |= (lane == first) ? (1u << bk) : 0u;
    sum += sqrtf(fmaxf(__uint_as_float(m), 1e-12f));
  }
  if (lane == 0) batch_sums[b] = sum;
}

// ---------- finalize ----------
__global__ void emd_finalize_kernel(const float* __restrict__ batch_sums,
                                    float* __restrict__ out, int B) {
  float acc = 0.f;
  for (int b = 0; b < B; ++b) acc += batch_sums[b] / (float)NPTS;
  out[0] = acc / (float)B;
}

extern "C" void kernel_launch(void* const* d_in, const int* in_sizes, int n_in,
                              void* d_out, int out_size, void* d_ws, size_t ws_size,
                              hipStream_t stream) {
  const float* pred   = (const float*)d_in[0];
  const float* target = (const float*)d_in[1];
  float* out = (float*)d_out;
  const int B = in_sizes[0] / (NPTS * 3);

  const size_t listsBytes = (size_t)B * NPTS * TOPK * sizeof(u64);
  const size_t need = 256 + listsBytes + (size_t)B * (64 * 4 + 16);
  if (ws_size >= need) {
    float* bs = (float*)d_ws;
    u64* lists = (u64*)((char*)d_ws + 256);
    u32* bmws = (u32*)((char*)d_ws + 256 + listsBytes);
    float* psumws = (float*)((char*)d_ws + 256 + listsBytes + (size_t)B * 64 * 4);
    emd_topk_kernel<<<B * (NPTS / RPB), 64, 0, stream>>>(pred, target, lists);
    emd_seq_part<0, SPLITB, false><<<B, 256, 0, stream>>>(
        pred, target, lists, bmws, psumws, bs);
    emd_seq_part<SPLITB, MAINBLKS, true><<<B, 256, 0, stream>>>(
        pred, target, lists, bmws, psumws, bs);
    emd_finalize_kernel<<<1, 1, 0, stream>>>(bs, out, B);
  } else {
    float* bs = (float*)d_ws;
    emd_greedy_kernel<<<B, 64, 0, stream>>>(pred, target, bs);
    emd_finalize_kernel<<<1, 1, 0, stream>>>(bs, out, B);
  }
}

// Round 17
// 372.342 us; speedup vs baseline: 1.1085x; 1.1085x over previous
//
#include <hip/hip_runtime.h>

#define NPTS 2048
#define TOPK 32
#define RPB  8        // rows per block in phase 1
#define MAINBLKS 30   // fixpoint blocks; tail handled densely
#define TAILROWS (NPTS - MAINBLKS * 64)  // 128

typedef float v2f __attribute__((ext_vector_type(2)));
typedef unsigned int u32;
typedef u32 v2u __attribute__((ext_vector_type(2)));
typedef unsigned long long u64;

// ---------- helpers ----------
static __device__ __forceinline__ u32 umin32(u32 a, u32 b) { return b < a ? b : a; }
static __device__ __forceinline__ u64 umin64(u64 a, u64 b) { return b < a ? b : a; }

template <int CTRL>
static __device__ __forceinline__ u32 dpp_min(u32 m) {
  return umin32(m, (u32)__builtin_amdgcn_mov_dpp((int)m, CTRL, 0xF, 0xF, true));
}
static __device__ __forceinline__ u32 x16_min(u32 m) {
#if __has_builtin(__builtin_amdgcn_permlane16_swap)
  auto r = __builtin_amdgcn_permlane16_swap((int)m, (int)m, false, false);
  return umin32(m, umin32((u32)r[0], (u32)r[1]));
#else
  return umin32(m, (u32)__builtin_amdgcn_ds_swizzle((int)m, 0x401F));
#endif
}
static __device__ __forceinline__ u32 x32_min(u32 m) {
#if __has_builtin(__builtin_amdgcn_permlane32_swap)
  auto r = __builtin_amdgcn_permlane32_swap((int)m, (int)m, false, false);
  return umin32(m, umin32((u32)r[0], (u32)r[1]));
#else
  return umin32(m, (u32)__shfl_xor((int)m, 32, 64));
#endif
}
static __device__ __forceinline__ u32 sext_bit(u32 mask, int c) {
#if __has_builtin(__builtin_amdgcn_sbfe)
  return (u32)__builtin_amdgcn_sbfe((int)mask, c, 1);
#else
  return (u32)(((int)(mask << (31 - c))) >> 31);
#endif
}

template <int CTRL>
static __device__ __forceinline__ u64 dpp_min64(u64 k) {
  unsigned lo = (unsigned)k, hi = (unsigned)(k >> 32);
  unsigned olo = (unsigned)__builtin_amdgcn_mov_dpp((int)lo, CTRL, 0xF, 0xF, true);
  unsigned ohi = (unsigned)__builtin_amdgcn_mov_dpp((int)hi, CTRL, 0xF, 0xF, true);
  return umin64(k, ((u64)ohi << 32) | olo);
}
static __device__ __forceinline__ u64 x16_min64(u64 k) {
  unsigned lo = (unsigned)k, hi = (unsigned)(k >> 32);
#if __has_builtin(__builtin_amdgcn_permlane16_swap)
  auto rlo = __builtin_amdgcn_permlane16_swap(lo, lo, false, false);
  auto rhi = __builtin_amdgcn_permlane16_swap(hi, hi, false, false);
  u64 a = ((u64)rhi[0] << 32) | rlo[0];
  u64 b = ((u64)rhi[1] << 32) | rlo[1];
  return umin64(k, umin64(a, b));
#else
  unsigned olo = (unsigned)__builtin_amdgcn_ds_swizzle((int)lo, 0x401F);
  unsigned ohi = (unsigned)__builtin_amdgcn_ds_swizzle((int)hi, 0x401F);
  return umin64(k, ((u64)ohi << 32) | olo);
#endif
}
static __device__ __forceinline__ u64 x32_min64(u64 k) {
  unsigned lo = (unsigned)k, hi = (unsigned)(k >> 32);
#if __has_builtin(__builtin_amdgcn_permlane32_swap)
  auto rlo = __builtin_amdgcn_permlane32_swap(lo, lo, false, false);
  auto rhi = __builtin_amdgcn_permlane32_swap(hi, hi, false, false);
  u64 a = ((u64)rhi[0] << 32) | rlo[0];
  u64 b = ((u64)rhi[1] << 32) | rlo[1];
  return umin64(k, umin64(a, b));
#else
  unsigned olo = (unsigned)__shfl_xor((int)lo, 32, 64);
  unsigned ohi = (unsigned)__shfl_xor((int)hi, 32, 64);
  return umin64(k, ((u64)ohi << 32) | olo);
#endif
}
static __device__ __forceinline__ u64 wave_min_u64(u64 k) {
  k = dpp_min64<0xB1>(k);
  k = dpp_min64<0x4E>(k);
  k = dpp_min64<0x141>(k);
  k = dpp_min64<0x140>(k);
  k = x16_min64(k);
  k = x32_min64(k);
  return k;  // wave-uniform
}

#define FOR16(M) M(0) M(1) M(2) M(3) M(4) M(5) M(6) M(7) \
                 M(8) M(9) M(10) M(11) M(12) M(13) M(14) M(15)

// Lane's 32 target columns in NAMED registers, as float2 pairs.
#define LOADP(h) \
  v2f TX##h, TY##h, TZ##h, TQ##h; \
  { float x0 = tb[6*h+0], y0 = tb[6*h+1], z0 = tb[6*h+2]; \
    float x1 = tb[6*h+3], y1 = tb[6*h+4], z1 = tb[6*h+5]; \
    TX##h = (v2f){x0, x1}; TY##h = (v2f){y0, y1}; TZ##h = (v2f){z0, z1}; \
    TQ##h = (v2f){x0*x0 + y0*y0 + z0*z0, x1*x1 + y1*y1 + z1*z1}; }

// ---------- phase 1: exact per-row sorted top-32, incremental tree ----------
#define DISTK(h) u64 KA##h, KB##h; { \
  v2f dot = __builtin_elementwise_fma(TX##h, Xv, \
              __builtin_elementwise_fma(TY##h, Yv, TZ##h * Zv)); \
  v2f dd  = __builtin_elementwise_fma(m2v, dot, TQ##h); \
  v2f d2  = Qv + dd; \
  float c0 = fmaxf(d2.x, 1e-12f), c1 = fmaxf(d2.y, 1e-12f); \
  KA##h = ((u64)(u32)__float_as_int(c0) << 32) | (u32)(base + 2*(h)); \
  KB##h = ((u64)(u32)__float_as_int(c1) << 32) | (u32)(base + 2*(h) + 1); }

#define G4(a, b, c, d) umin64(umin64(a, b), umin64(c, d))
#define ZG(c, KV, RL) case (c): KV = own ? ~0ULL : KV; goto RL;

__global__ __launch_bounds__(64, 2) void emd_topk_kernel(
    const float* __restrict__ pred, const float* __restrict__ target,
    u64* __restrict__ lists) {
  const int blk = blockIdx.x;
  const int b  = blk / (NPTS / RPB);
  const int r0 = (blk % (NPTS / RPB)) * RPB;
  const int lane = threadIdx.x;
  const float* p = pred + (size_t)b * NPTS * 3;
  const float* t = target + (size_t)b * NPTS * 3;

  const float* tb = t + (size_t)lane * 32 * 3;
  FOR16(LOADP)
  const int base = lane << 5;
  const v2f m2v = {-2.f, -2.f};

#pragma unroll 1
  for (int rr = 0; rr < RPB; ++rr) {
    const int i = r0 + rr;
    const float X = p[3 * i], Y = p[3 * i + 1], Z = p[3 * i + 2];
    const float Q = fmaf(X, X, fmaf(Y, Y, Z * Z));
    const v2f Xv = {X, X}, Yv = {Y, Y}, Zv = {Z, Z}, Qv = {Q, Q};
    FOR16(DISTK)

    u64 g0 = G4(KA0, KB0, KA1, KB1),   g1 = G4(KA2, KB2, KA3, KB3);
    u64 g2 = G4(KA4, KB4, KA5, KB5),   g3 = G4(KA6, KB6, KA7, KB7);
    u64 g4 = G4(KA8, KB8, KA9, KB9),   g5 = G4(KA10, KB10, KA11, KB11);
    u64 g6 = G4(KA12, KB12, KA13, KB13), g7 = G4(KA14, KB14, KA15, KB15);
    u64 h0 = umin64(g0, g1), h1 = umin64(g2, g3);
    u64 h2 = umin64(g4, g5), h3 = umin64(g6, g7);
    u64 q0 = umin64(h0, h1), q1 = umin64(h2, h3);
    u64 root = umin64(q0, q1);

    u64* out = lists + ((size_t)b * NPTS + i) * TOPK;
#pragma unroll 1
    for (int e = 0; e < TOPK; ++e) {
      u64 m = wave_min_u64(root);
      if (lane == 0) out[e] = m;
      if (e == TOPK - 1) break;
      const u32 col = (u32)m & (u32)(NPTS - 1);  // wave-uniform
      const bool own = (lane == (int)(col >> 5));
      const u32 k5 = col & 31u;
      switch (k5) {
        ZG(0,  KA0,  R0) ZG(1,  KB0,  R0) ZG(2,  KA1,  R0) ZG(3,  KB1,  R0)
        ZG(4,  KA2,  R1) ZG(5,  KB2,  R1) ZG(6,  KA3,  R1) ZG(7,  KB3,  R1)
        ZG(8,  KA4,  R2) ZG(9,  KB4,  R2) ZG(10, KA5,  R2) ZG(11, KB5,  R2)
        ZG(12, KA6,  R3) ZG(13, KB6,  R3) ZG(14, KA7,  R3) ZG(15, KB7,  R3)
        ZG(16, KA8,  R4) ZG(17, KB8,  R4) ZG(18, KA9,  R4) ZG(19, KB9,  R4)
        ZG(20, KA10, R5) ZG(21, KB10, R5) ZG(22, KA11, R5) ZG(23, KB11, R5)
        ZG(24, KA12, R6) ZG(25, KB12, R6) ZG(26, KA13, R6) ZG(27, KB13, R6)
        ZG(28, KA14, R7) ZG(29, KB14, R7) ZG(30, KA15, R7) ZG(31, KB15, R7)
        default: __builtin_unreachable();
      }
      R0: g0 = G4(KA0, KB0, KA1, KB1);     h0 = umin64(g0, g1); q0 = umin64(h0, h1); root = umin64(q0, q1); continue;
      R1: g1 = G4(KA2, KB2, KA3, KB3);     h0 = umin64(g0, g1); q0 = umin64(h0, h1); root = umin64(q0, q1); continue;
      R2: g2 = G4(KA4, KB4, KA5, KB5);     h1 = umin64(g2, g3); q0 = umin64(h0, h1); root = umin64(q0, q1); continue;
      R3: g3 = G4(KA6, KB6, KA7, KB7);     h1 = umin64(g2, g3); q0 = umin64(h0, h1); root = umin64(q0, q1); continue;
      R4: g4 = G4(KA8, KB8, KA9, KB9);     h2 = umin64(g4, g5); q1 = umin64(h2, h3); root = umin64(q0, q1); continue;
      R5: g5 = G4(KA10, KB10, KA11, KB11); h2 = umin64(g4, g5); q1 = umin64(h2, h3); root = umin64(q0, q1); continue;
      R6: g6 = G4(KA12, KB12, KA13, KB13); h3 = umin64(g6, g7); q1 = umin64(h2, h3); root = umin64(q0, q1); continue;
      R7: g7 = G4(KA14, KB14, KA15, KB15); h3 = umin64(g6, g7); q1 = umin64(h2, h3); root = umin64(q0, q1); continue;
    }
  }
}

// ---------- phase 2: pipelined DA, register-bitmap gathers ----------
// Single kernel (split reverted). 4 waves: wave0 consumer, waves1-3
// producers (round 15 layout). The bitmap is gathered via one ordered
// read per lane + __shfl (ds_bpermute, pipelined) instead of 32
// serialized volatile LDS reads — the round-16 diagnostic showed the
// per-block cost is uniform fabric, i.e. these dependent chains.

#define LD16(M) M(0) M(1) M(2) M(3) M(4) M(5) M(6) M(7) \
                M(8) M(9) M(10) M(11) M(12) M(13) M(14) M(15)
#define DECLA(j) uint4 A##j;
#define LDA(j)   A##j = Lr[j];
#define WRCD(j)  { dst[(2*(j)) * 64 + lane]     = ((u64)A##j.y << 32) | A##j.x; \
                   dst[(2*(j) + 1) * 64 + lane] = ((u64)A##j.w << 32) | A##j.z; }

#define ADVANCE() { \
    alive &= ~(1u << rank); \
    if (alive == 0u) { exh = true; } \
    else { \
      rank = (u32)__ffs(alive) - 1u; \
      cur = cl[rank * 64 + lane]; \
      col = (u32)cur & 2047u; \
    } }

// atomicMin-return cascade: chase hop = 1 LDS atomic (returns old).
#define CASCADE() { \
    int guard_ = 0; \
    while (true) { \
      bool changed_ = false; \
      if (!committed && !exh) { \
        if (holding && vclaim[col] < (u32)lane) { \
          holding = false; \
          ADVANCE() \
          changed_ = true; \
        } \
        int g2_ = 0; \
        while (!holding && !exh) { \
          u32 old_ = atomicMin(&claimCur[col], (u32)lane); \
          if (old_ >= (u32)lane) { holding = true; break; } \
          ADVANCE() \
          changed_ = true; \
          if (++g2_ > 40) break; \
        } \
      } \
      if (__ballot(changed_) == 0ULL) break; \
      if (++guard_ > 3000) break; \
    } }

__global__ __launch_bounds__(256, 1) void emd_seq_kernel(
    const float* __restrict__ pred, const float* __restrict__ target,
    const u64* __restrict__ lists, float* __restrict__ batch_sums) {
  const int b = blockIdx.x;
  const int tid = threadIdx.x;
  const int w = tid >> 6, lane = tid & 63;
  const float* t = target + (size_t)b * NPTS * 3;
  const float* p = pred + (size_t)b * NPTS * 3;

  __shared__ float4 tt[NPTS];          // 32 KB
  __shared__ u64 cl64s[2][TOPK * 64];  // 32 KB
  __shared__ u32 claimb[2][NPTS];      // 16 KB
  __shared__ u32 fl[NPTS];             // 8 KB
  __shared__ u32 sbitmap[64];
  __shared__ float4 ppredb[2][64];
  __shared__ float4 tpred[TAILROWS];

  for (int j = tid; j < NPTS; j += 256) {
    float x = t[3 * j], y = t[3 * j + 1], z = t[3 * j + 2];
    tt[((j & 31) << 6) | ((j >> 5) ^ (j & 31))] =
        make_float4(x, y, z, fmaf(x, x, fmaf(y, y, z * z)));
  }
  if (tid < 64) sbitmap[tid] = 0u;

  const u64* L = lists + (size_t)b * NPTS * TOPK;
  volatile u32* sbmv = sbitmap;
  float psum = 0.f;

  const uint4* Lr;
  LD16(DECLA)

  // ---- prologue staging (block 0 into buffer 0; wave1 prefetches block 1) ----
  if (w == 1) {
    Lr = (const uint4*)(L + (size_t)lane * TOPK);
    LD16(LDA)
    u64* dst = &cl64s[0][0];
    LD16(WRCD)
    Lr = (const uint4*)(L + (size_t)(64 + lane) * TOPK);
    LD16(LDA)
  } else if (w == 2) {
#pragma unroll
    for (int k = 0; k < 32; ++k) claimb[0][k * 64 + lane] = ~0u;
  } else if (w == 3) {
    { const float* pr = p + (size_t)lane * 3;
      float X = pr[0], Y = pr[1], Z = pr[2];
      ppredb[0][lane] = make_float4(X, Y, Z, fmaf(X, X, fmaf(Y, Y, Z * Z))); }
    { const float* pr = p + (size_t)(MAINBLKS * 64 + lane) * 3;
      float X = pr[0], Y = pr[1], Z = pr[2];
      tpred[lane] = make_float4(X, Y, Z, fmaf(X, X, fmaf(Y, Y, Z * Z))); }
    { const float* pr = p + (size_t)(MAINBLKS * 64 + 64 + lane) * 3;
      float X = pr[0], Y = pr[1], Z = pr[2];
      tpred[64 + lane] = make_float4(X, Y, Z, fmaf(X, X, fmaf(Y, Y, Z * Z))); }
  }

#pragma unroll 1
  for (int blk = 0; blk < MAINBLKS; ++blk) {
    __syncthreads();  // buffer blk&1 fully staged

    if (w == 1) {
      if (blk + 1 < MAINBLKS) {
        u64* dst = &cl64s[(blk + 1) & 1][0];
        LD16(WRCD)
        if (blk + 2 < MAINBLKS) {
          Lr = (const uint4*)(L + (size_t)((blk + 2) * 64 + lane) * TOPK);
          LD16(LDA)
        }
      }
    } else if (w == 2) {
      if (blk + 1 < MAINBLKS) {
#pragma unroll
        for (int k = 0; k < 32; ++k) claimb[(blk + 1) & 1][k * 64 + lane] = ~0u;
      }
    } else if (w == 3) {
      if (blk + 1 < MAINBLKS) {
        const float* pr = p + (size_t)((blk + 1) * 64 + lane) * 3;
        float X = pr[0], Y = pr[1], Z = pr[2];
        ppredb[(blk + 1) & 1][lane] =
            make_float4(X, Y, Z, fmaf(X, X, fmaf(Y, Y, Z * Z)));
      }
    } else {  // w == 0: consumer
      const u64* cl = &cl64s[blk & 1][0];
      u32* claimCur = &claimb[blk & 1][0];
      volatile u32* vclaim = claimCur;
      const float4* ppcur = &ppredb[blk & 1][0];

      // Bitmap snapshot (stable since last commit) -> register; gathers
      // via shfl/bpermute pipeline instead of serialized volatile reads.
      u32 bmw = sbmv[lane];
      u32 alive = 0u;
#pragma unroll
      for (int j = 0; j < 32; ++j) {
        u32 c = (u32)cl[j * 64 + lane] & 2047u;
        u32 wd = (u32)__shfl((int)bmw, (int)(c >> 5), 64);
        alive |= ((~(wd >> (c & 31u))) & 1u) << j;
      }

      bool committed = false;
      bool holding = false;
      bool exh = (alive == 0u);
      u32 rank = 0, col = 0;
      u64 cur = 0;
      if (!exh) {
        rank = (u32)__ffs(alive) - 1u;
        cur = cl[rank * 64 + lane];
        col = (u32)cur & 2047u;
      }
      CASCADE()

      bool flBuilt = false;
      u32 F = 0;
      int oguard = 0;
#pragma unroll 1
      while (true) {
        u64 exbl = __ballot(exh && !committed);
        if (exbl == 0ULL) break;
        int rstar = __ffsll(exbl) - 1;

        if (!committed && !exh && lane < rstar) {
          atomicOr(&sbitmap[col >> 5], 1u << (col & 31u));
          psum += sqrtf(__uint_as_float((u32)(cur >> 32)));
          committed = true;
        }

        if (!flBuilt) {
          u32 fw = ~sbmv[lane];
          u32 cnt = __popc(fw);
          u32 pfx = cnt;
#pragma unroll
          for (int d = 1; d < 64; d <<= 1) {
            u32 o = (u32)__shfl_up((int)pfx, d, 64);
            if (lane >= d) pfx += o;
          }
          F = (u32)__shfl((int)pfx, 63, 64);
          pfx -= cnt;
          while (fw) {
            int bpos = __ffs(fw) - 1;
            fw &= fw - 1u;
            fl[pfx++] = ((u32)lane << 5) + (u32)bpos;
          }
          flBuilt = true;
        }

        u32 cst;
        {
          // fresh snapshot (ordered volatile read), then pipelined gathers
          u32 bm2 = sbmv[lane];
          float4 P4 = ppcur[rstar];
          float X = P4.x, Y = P4.y, Z = P4.z, Q = P4.w;
          u64 mb = ~0ULL;
          for (u32 k = (u32)lane; k < F; k += 64) {
            u32 c = fl[k];
            u32 wd = (u32)__shfl((int)bm2, (int)(c >> 5), 64);
            u32 used = (wd >> (c & 31u)) & 1u;
            float4 c4 = tt[((c & 31u) << 6) | ((c >> 5) ^ (c & 31u))];
            float dot = fmaf(c4.x, X, fmaf(c4.y, Y, c4.z * Z));
            float d2 = Q + fmaf(-2.f, dot, c4.w);
            d2 = fmaxf(d2, 1e-12f);
            u64 kk = ((u64)(u32)__float_as_int(d2) << 32) | c;
            if (used) kk = ~0ULL;
            mb = umin64(mb, kk);
          }
          mb = wave_min_u64(mb);
          cst = (u32)mb & 2047u;
          if (lane == rstar) {
            psum += sqrtf(__uint_as_float((u32)(mb >> 32)));
            committed = true;
          }
        }
        u32 prev = vclaim[cst];
        if (lane == rstar) {
          atomicOr(&sbitmap[cst >> 5], 1u << (cst & 31u));
          atomicMin(&claimCur[cst], (u32)rstar);
        }
        if (prev != ~0u) {
          CASCADE()
        }
        if (++oguard > 80) break;
      }

      if (!committed) {
        atomicOr(&sbitmap[col >> 5], 1u << (col & 31u));
        psum += sqrtf(__uint_as_float((u32)(cur >> 32)));
      }
    }
  }

  __syncthreads();

  // ---- dense register tail on wave 0 ----
  if (w == 0) {
    u32 fw = ~sbmv[lane];
    u32 cnt = __popc(fw);
    u32 pfx = cnt;
#pragma unroll
    for (int d = 1; d < 64; d <<= 1) {
      u32 o = (u32)__shfl_up((int)pfx, d, 64);
      if (lane >= d) pfx += o;
    }
    u32 F = (u32)__shfl((int)pfx, 63, 64);
    pfx -= cnt;
    while (fw) {
      int bpos = __ffs(fw) - 1;
      fw &= fw - 1u;
      fl[pfx++] = ((u32)lane << 5) + (u32)bpos;
    }

    bool l0 = (u32)lane < F, l1 = (u32)(64 + lane) < F;
    u32 c0 = l0 ? fl[lane] : 0u;
    u32 c1 = l1 ? fl[64 + lane] : 0u;
    float4 t0 = tt[((c0 & 31u) << 6) | ((c0 >> 5) ^ (c0 & 31u))];
    float4 t1 = tt[((c1 & 31u) << 6) | ((c1 >> 5) ^ (c1 & 31u))];

#pragma unroll 1
    for (int r = 0; r < TAILROWS; ++r) {
      float4 P = tpred[r];
      float X = P.x, Y = P.y, Z = P.z, Q = P.w;
      float dot0 = fmaf(t0.x, X, fmaf(t0.y, Y, t0.z * Z));
      float d20 = fmaxf(Q + fmaf(-2.f, dot0, t0.w), 1e-12f);
      float dot1 = fmaf(t1.x, X, fmaf(t1.y, Y, t1.z * Z));
      float d21 = fmaxf(Q + fmaf(-2.f, dot1, t1.w), 1e-12f);
      u64 k0 = l0 ? (((u64)(u32)__float_as_int(d20) << 32) | c0) : ~0ULL;
      u64 k1 = l1 ? (((u64)(u32)__float_as_int(d21) << 32) | c1) : ~0ULL;
      u64 k = wave_min_u64(umin64(k0, k1));
      u32 wc = (u32)k & 2047u;
      l0 = l0 && (c0 != wc);
      l1 = l1 && (c1 != wc);
      if (lane == 0) psum += sqrtf(__uint_as_float((u32)(k >> 32)));
    }

    float v = psum;
    v += __shfl_xor(v, 1, 64);
    v += __shfl_xor(v, 2, 64);
    v += __shfl_xor(v, 4, 64);
    v += __shfl_xor(v, 8, 64);
    v += __shfl_xor(v, 16, 64);
    v += __shfl_xor(v, 32, 64);
    if (lane == 0) batch_sums[b] = v;
  }
}

// ---------- legacy single-kernel path (round-5, proven; ws-too-small) ----------
#define DECLRU(h) v2u RU##h;
#define DIST(h) { \
  v2f dot = __builtin_elementwise_fma(TX##h, Xv, \
              __builtin_elementwise_fma(TY##h, Yv, TZ##h * Zv)); \
  v2f dd  = __builtin_elementwise_fma(m2v, dot, TQ##h); \
  v2f d2  = Qv + dd; \
  RU##h = (v2u){(u32)__float_as_int(d2.x), (u32)__float_as_int(d2.y)}; }
#define TOUR(h, c) { \
  u32 u0 = RU##h.x | sext_bit(usedmask, 2*h); \
  u32 u1 = RU##h.y | sext_bit(usedmask, 2*h + 1); \
  u32 pu = umin32(u0, u1); \
  u32 pk = (u1 < u0) ? (u32)(2*h + 1) : (u32)(2*h); \
  if (pu < bc##c) { bc##c = pu; kc##c = pk; } }

__global__ __launch_bounds__(64, 1) void emd_greedy_kernel(
    const float* __restrict__ pred, const float* __restrict__ target,
    float* __restrict__ batch_sums) {
  const int b = blockIdx.x, lane = threadIdx.x;
  const float* p = pred + (size_t)b * NPTS * 3;
  const float* t = target + (size_t)b * NPTS * 3;
  __shared__ float4 pp[NPTS + 2];
  for (int i = lane; i < NPTS; i += 64) {
    float x = p[3 * i], y = p[3 * i + 1], z = p[3 * i + 2];
    pp[i] = make_float4(x, y, z, x * x + y * y + z * z);
  }
  if (lane < 2) pp[NPTS + lane] = make_float4(0.f, 0.f, 0.f, 0.f);
  const float* tb = t + (size_t)lane * 32 * 3;
  FOR16(LOADP)
  FOR16(DECLRU)
  u32 usedmask = 0;
  float sum = 0.f;
  __syncthreads();
  const v2f m2v = {-2.f, -2.f};
  v2f Xv, Yv, Zv, Qv;
  {
    float4 A = pp[0];
    Xv = (v2f){A.x, A.x}; Yv = (v2f){A.y, A.y};
    Zv = (v2f){A.z, A.z}; Qv = (v2f){A.w, A.w};
    FOR16(DIST)
  }
  for (int i = 0; i < NPTS; ++i) {
    float4 An = pp[i + 1];
    u32 bc0 = ~0u, bc1 = ~0u, bc2 = ~0u, bc3 = ~0u;
    u32 kc0 = 0, kc1 = 0, kc2 = 0, kc3 = 0;
    TOUR(0, 0)  TOUR(1, 0)  TOUR(2, 0)  TOUR(3, 0)
    TOUR(4, 1)  TOUR(5, 1)  TOUR(6, 1)  TOUR(7, 1)
    TOUR(8, 2)  TOUR(9, 2)  TOUR(10, 2) TOUR(11, 2)
    TOUR(12, 3) TOUR(13, 3) TOUR(14, 3) TOUR(15, 3)
    bool s01 = bc1 < bc0; u32 v01 = s01 ? bc1 : bc0; u32 i01 = s01 ? kc1 : kc0;
    bool s23 = bc3 < bc2; u32 v23 = s23 ? bc3 : bc2; u32 i23 = s23 ? kc3 : kc2;
    bool sf  = v23 < v01; u32 bu  = sf ? v23 : v01; u32 bk  = sf ? i23 : i01;
    Xv = (v2f){An.x, An.x}; Yv = (v2f){An.y, An.y};
    Zv = (v2f){An.z, An.z}; Qv = (v2f){An.w, An.w};
    FOR16(DIST)
    u32 m = bu;
    m = dpp_min<0xB1>(m); m = dpp_min<0x4E>(m);
    m = dpp_min<0x141>(m); m = dpp_min<0x140>(m);
    m = x16_min(m); m = x32_min(m);
    u64 mk = __ballot(bu == m);
    int first = __ffsll(mk) - 1;
    usedmask |= (lane == first) ? (1u << bk) : 0u;
    sum += sqrtf(fmaxf(__uint_as_float(m), 1e-12f));
  }
  if (lane == 0) batch_sums[b] = sum;
}

// ---------- finalize ----------
__global__ void emd_finalize_kernel(const float* __restrict__ batch_sums,
                                    float* __restrict__ out, int B) {
  float acc = 0.f;
  for (int b = 0; b < B; ++b) acc += batch_sums[b] / (float)NPTS;
  out[0] = acc / (float)B;
}

extern "C" void kernel_launch(void* const* d_in, const int* in_sizes, int n_in,
                              void* d_out, int out_size, void* d_ws, size_t ws_size,
                              hipStream_t stream) {
  const float* pred   = (const float*)d_in[0];
  const float* target = (const float*)d_in[1];
  float* out = (float*)d_out;
  const int B = in_sizes[0] / (NPTS * 3);

  const size_t need = 256 + (size_t)B * NPTS * TOPK * sizeof(u64);
  if (ws_size >= need) {
    float* bs = (float*)d_ws;
    u64* lists = (u64*)((char*)d_ws + 256);
    emd_topk_kernel<<<B * (NPTS / RPB), 64, 0, stream>>>(pred, target, lists);
    emd_seq_kernel<<<B, 256, 0, stream>>>(pred, target, lists, bs);
    emd_finalize_kernel<<<1, 1, 0, stream>>>(bs, out, B);
  } else {
    float* bs = (float*)d_ws;
    emd_greedy_kernel<<<B, 64, 0, stream>>>(pred, target, bs);
    emd_finalize_kernel<<<1, 1, 0, stream>>>(bs, out, B);
  }
}